// Round 7
// baseline (83.317 us; speedup 1.0000x reference)
//
#include <hip/hip_runtime.h>
#include <stdint.h>

#define IN_F   8192
#define OUT_F  8192
#define M_TOK  32
#define BN     32      // output channels per block (grid 256 = 1 block/CU)
#define BK     256     // K elements staged per iteration (1KB/row stream burst)
#define NIT    (IN_F / BK)   // 32
#define LDSS   264     // BK + 8 pad (528B row stride -> same free 2-way alias class)

typedef float  f32x4  __attribute__((ext_vector_type(4)));
typedef short  short8 __attribute__((ext_vector_type(8)));

// Barrier without vmcnt drain: LDS writes ordered, global prefetch stays in flight.
#define LDS_BARRIER() do {                                   \
    asm volatile("s_waitcnt lgkmcnt(0)" ::: "memory");       \
    __builtin_amdgcn_s_barrier();                            \
} while (0)

// pack two fp32 into two bf16 (truncation; exact for int8-valued floats;
// measured absmax 4.0 vs threshold 13.12 across rounds 2/4/5/6)
__device__ inline unsigned pk_bf16(float f0, float f1) {
    unsigned u0 = __builtin_bit_cast(unsigned, f0);
    unsigned u1 = __builtin_bit_cast(unsigned, f1);
    return (u0 >> 16) | (u1 & 0xFFFF0000u);
}

// R2 structure (52.8us baseline), single change: BK 128->256, PF 2->1.
// Halves iteration count (amortizes per-iter serial overhead) and doubles
// the per-stream DRAM burst (page locality). PF=1 is sound: steady-state
// pace/iter ~2740cy > ~900cy HBM latency; 64KB/CU in flight >> BW-delay.
__global__ __launch_bounds__(256, 1) void qlin_mfma(
    const float* __restrict__ x, const int* __restrict__ wq,
    const float* __restrict__ scale, float* __restrict__ out) {

    __shared__ ushort ldsA[2][M_TOK][LDSS];  // x tile bf16 (33 KB)
    __shared__ ushort ldsW[2][BN][LDSS];     // W tile bf16 (33 KB)

    const int t  = threadIdx.x;
    const int o0 = blockIdx.x * BN;

    // staging: 256 threads -> 32 rows x 8 chunks of 32 elements (128B/thread)
    const int r  = t >> 3;          // row 0..31
    const int cc = (t & 7) * 32;    // element col base 0..224

    const float* xp = x  + (size_t)r * IN_F + cc;
    const int*   wp = wq + (size_t)(o0 + r) * IN_F + cc;   // int8-valued, stored int32

    float4 abuf[8];   // 32 fp32 / thread / iter
    int4   wbuf[8];   // 32 int32 / thread / iter

    #pragma unroll
    for (int q = 0; q < 8; ++q) {
        abuf[q] = *reinterpret_cast<const float4*>(xp + 4 * q);
        wbuf[q] = *reinterpret_cast<const int4*>(wp + 4 * q);
    }

    // compute decomposition: 4 waves, one 16x16 output tile each
    const int wid  = t >> 6;
    const int lane = t & 63;
    const int mt   = wid & 1;          // token half
    const int nt   = wid >> 1;         // channel half
    const int frow = lane & 15;
    const int fk   = (lane >> 4) * 8;

    f32x4 acc = {0.f, 0.f, 0.f, 0.f};

    for (int it = 0; it < NIT; ++it) {
        const int buf = it & 1;

        // ---- stage x (fp32 -> bf16): 32 elems -> 4x uint4 ----
        #pragma unroll
        for (int h = 0; h < 4; ++h) {
            float4 v0 = abuf[2 * h], v1 = abuf[2 * h + 1];
            uint4 w0;
            w0.x = pk_bf16(v0.x, v0.y); w0.y = pk_bf16(v0.z, v0.w);
            w0.z = pk_bf16(v1.x, v1.y); w0.w = pk_bf16(v1.z, v1.w);
            *reinterpret_cast<uint4*>(&ldsA[buf][r][cc + 8 * h]) = w0;
        }
        // ---- stage W (int32 -> bf16; exact, |v| <= 128) ----
        #pragma unroll
        for (int h = 0; h < 4; ++h) {
            int4 a0 = wbuf[2 * h], a1 = wbuf[2 * h + 1];
            uint4 w0;
            w0.x = pk_bf16((float)a0.x, (float)a0.y);
            w0.y = pk_bf16((float)a0.z, (float)a0.w);
            w0.z = pk_bf16((float)a1.x, (float)a1.y);
            w0.w = pk_bf16((float)a1.z, (float)a1.w);
            *reinterpret_cast<uint4*>(&ldsW[buf][r][cc + 8 * h]) = w0;
        }

        // ---- issue next iteration's loads (complete during this compute;
        //      survive the lgkm-only barrier) ----
        if (it + 1 < NIT) {
            const size_t off = (size_t)(it + 1) * BK;
            #pragma unroll
            for (int q = 0; q < 8; ++q) {
                abuf[q] = *reinterpret_cast<const float4*>(xp + off + 4 * q);
                wbuf[q] = *reinterpret_cast<const int4*>(wp + off + 4 * q);
            }
        }

        LDS_BARRIER();   // lgkm-only: prefetch not drained

        // ---- compute: 8 K-substeps of 32 ----
        const ushort* aB = &ldsA[buf][mt * 16 + frow][fk];
        const ushort* wB = &ldsW[buf][nt * 16 + frow][fk];
        #pragma unroll
        for (int ks = 0; ks < 8; ++ks) {
            short8 af = *reinterpret_cast<const short8*>(aB + ks * 32);
            short8 bf = *reinterpret_cast<const short8*>(wB + ks * 32);
            acc = __builtin_amdgcn_mfma_f32_16x16x32_bf16(af, bf, acc, 0, 0, 0);
        }
        // single barrier/iter: same-buffer WAR separated by the next barrier
    }

    // ---- epilogue: per-channel scale, store ----
    // C/D layout (m89-verified): col = lane&15, row = (lane>>4)*4 + reg
    const int ocol = o0 + nt * 16 + frow;
    const float s  = scale[ocol];
    const int  m0  = mt * 16 + (lane >> 4) * 4;
    #pragma unroll
    for (int rg = 0; rg < 4; ++rg)
        out[(size_t)(m0 + rg) * OUT_F + ocol] = acc[rg] * s;
}

extern "C" void kernel_launch(void* const* d_in, const int* in_sizes, int n_in,
                              void* d_out, int out_size, void* d_ws, size_t ws_size,
                              hipStream_t stream) {
    const float* x  = (const float*)d_in[0];
    const int*   wq = (const int*)d_in[1];   // int8-valued weights stored as int32
    const float* sc = (const float*)d_in[2];
    float* out = (float*)d_out;

    qlin_mfma<<<OUT_F / BN, 256, 0, stream>>>(x, wq, sc, out);
}

// Round 8
// 59.289 us; speedup vs baseline: 1.4053x; 1.4053x over previous
//
#include <hip/hip_runtime.h>
#include <stdint.h>

#define IN_F   8192
#define OUT_F  8192
#define M_TOK  32
#define BN     32               // output channels per block
#define KSPLIT 2                // K-split across blocks -> 2 blocks/CU (real TLP)
#define KLEN   (IN_F / KSPLIT)  // 4096
#define BK     128              // K elements staged per iteration
#define NIT    (KLEN / BK)      // 32
#define PF     2                // prefetch depth (issue-to-consume ~2 iters >> HBM latency)
#define LDSS   136              // 272B row stride -> free 2-way bank alias (m136)

typedef float  f32x4  __attribute__((ext_vector_type(4)));
typedef short  short8 __attribute__((ext_vector_type(8)));

// Barrier without vmcnt drain: LDS writes ordered, global prefetch stays in flight.
#define LDS_BARRIER() do {                                   \
    asm volatile("s_waitcnt lgkmcnt(0)" ::: "memory");       \
    __builtin_amdgcn_s_barrier();                            \
} while (0)

// pack two fp32 into two bf16 (truncation; exact for int8-valued floats;
// measured absmax 4.0 vs threshold 13.12 across rounds 2/4/5/6/7)
__device__ inline unsigned pk_bf16(float f0, float f1) {
    unsigned u0 = __builtin_bit_cast(unsigned, f0);
    unsigned u1 = __builtin_bit_cast(unsigned, f1);
    return (u0 >> 16) | (u1 & 0xFFFF0000u);
}

// R2 structure (52.8us proven), single lever: K-split over 2 blocks/CU.
// Same chip-wide traffic (W read once; x: 512 blocks x 512KB = 256MB = R2).
// Independent per-block barriers -> block B's loads/VALU overlap block A's
// barrier/ds_read/MFMA serial chain (the 540cy/iter measured exposure).
__global__ __launch_bounds__(256, 2) void qlin_part(
    const float* __restrict__ x, const int* __restrict__ wq,
    float* __restrict__ wsp) {

    __shared__ ushort ldsA[2][M_TOK][LDSS];  // x tile bf16 (17.4 KB)
    __shared__ ushort ldsW[2][BN][LDSS];     // W tile bf16 (17.4 KB)

    const int t  = threadIdx.x;
    const int b  = blockIdx.x >> 1;          // o-block 0..255
    const int kb = blockIdx.x & 1;           // K half
    const int o0 = b * BN;

    // staging: 256 threads -> 32 rows x 8 chunks of 16 elements (coalesced 512B/row)
    const int r  = t >> 3;          // row 0..31
    const int cc = (t & 7) * 16;    // element col base 0..112

    const float* xp = x  + (size_t)r * IN_F + (size_t)kb * KLEN + cc;
    const int*   wp = wq + (size_t)(o0 + r) * IN_F + (size_t)kb * KLEN + cc;

    float4 abuf[PF][4];   // 16 fp32 / thread / iter
    int4   wbuf[PF][4];   // 16 int32 / thread / iter

    #pragma unroll
    for (int p = 0; p < PF; ++p) {
        #pragma unroll
        for (int q = 0; q < 4; ++q) {
            abuf[p][q] = *reinterpret_cast<const float4*>(xp + p * BK + 4 * q);
            wbuf[p][q] = *reinterpret_cast<const int4*>(wp + p * BK + 4 * q);
        }
    }

    // compute decomposition: 4 waves, one 16x16 output tile each
    const int wid  = t >> 6;
    const int lane = t & 63;
    const int mt   = wid & 1;          // token half
    const int nt   = wid >> 1;         // channel half
    const int frow = lane & 15;
    const int fk   = (lane >> 4) * 8;

    f32x4 acc = {0.f, 0.f, 0.f, 0.f};

    for (int base = 0; base < NIT; base += PF) {
        #pragma unroll
        for (int p = 0; p < PF; ++p) {
            const int it  = base + p;
            const int buf = it & 1;

            // ---- stage x (fp32 -> bf16) ----
            {
                float4 v0 = abuf[p][0], v1 = abuf[p][1];
                float4 v2 = abuf[p][2], v3 = abuf[p][3];
                uint4 w0, w1;
                w0.x = pk_bf16(v0.x, v0.y); w0.y = pk_bf16(v0.z, v0.w);
                w0.z = pk_bf16(v1.x, v1.y); w0.w = pk_bf16(v1.z, v1.w);
                w1.x = pk_bf16(v2.x, v2.y); w1.y = pk_bf16(v2.z, v2.w);
                w1.z = pk_bf16(v3.x, v3.y); w1.w = pk_bf16(v3.z, v3.w);
                *reinterpret_cast<uint4*>(&ldsA[buf][r][cc])     = w0;
                *reinterpret_cast<uint4*>(&ldsA[buf][r][cc + 8]) = w1;
            }
            // ---- stage W (int32 -> bf16; exact, |v| <= 128) ----
            {
                int4 a0 = wbuf[p][0], a1 = wbuf[p][1];
                int4 a2 = wbuf[p][2], a3 = wbuf[p][3];
                uint4 w0, w1;
                w0.x = pk_bf16((float)a0.x, (float)a0.y);
                w0.y = pk_bf16((float)a0.z, (float)a0.w);
                w0.z = pk_bf16((float)a1.x, (float)a1.y);
                w0.w = pk_bf16((float)a1.z, (float)a1.w);
                w1.x = pk_bf16((float)a2.x, (float)a2.y);
                w1.y = pk_bf16((float)a2.z, (float)a2.w);
                w1.z = pk_bf16((float)a3.x, (float)a3.y);
                w1.w = pk_bf16((float)a3.z, (float)a3.w);
                *reinterpret_cast<uint4*>(&ldsW[buf][r][cc])     = w0;
                *reinterpret_cast<uint4*>(&ldsW[buf][r][cc + 8]) = w1;
            }

            // ---- issue loads PF iterations ahead ----
            const int nit = it + PF;
            if (nit < NIT) {
                #pragma unroll
                for (int q = 0; q < 4; ++q) {
                    abuf[p][q] = *reinterpret_cast<const float4*>(xp + nit * BK + 4 * q);
                    wbuf[p][q] = *reinterpret_cast<const int4*>(wp + nit * BK + 4 * q);
                }
            }

            LDS_BARRIER();   // lgkm-only: prefetch not drained

            // ---- compute: 4 K-substeps of 32 ----
            const ushort* aB = &ldsA[buf][mt * 16 + frow][fk];
            const ushort* wB = &ldsW[buf][nt * 16 + frow][fk];
            #pragma unroll
            for (int ks = 0; ks < 4; ++ks) {
                short8 af = *reinterpret_cast<const short8*>(aB + ks * 32);
                short8 bf = *reinterpret_cast<const short8*>(wB + ks * 32);
                acc = __builtin_amdgcn_mfma_f32_16x16x32_bf16(af, bf, acc, 0, 0, 0);
            }
            // single barrier/iter: same-buffer WAR separated by next barrier
        }
    }

    // ---- epilogue: store unscaled 32x32 partial tile to workspace ----
    // C/D layout (m89-verified): col = lane&15, row = (lane>>4)*4 + reg
    float* wsb = wsp + (size_t)blockIdx.x * (32 * 32);
    const int ocl = nt * 16 + frow;
    const int m0  = mt * 16 + (lane >> 4) * 4;
    #pragma unroll
    for (int rg = 0; rg < 4; ++rg)
        wsb[(m0 + rg) * 32 + ocl] = acc[rg];
}

// sum the two K-half partials, apply per-channel scale, store final output
__global__ __launch_bounds__(256) void qred(
    const float* __restrict__ wsp, const float* __restrict__ scale,
    float* __restrict__ out) {
    const int b  = blockIdx.x;       // o-block 0..255
    const int t  = threadIdx.x;
    const int m  = t >> 3;           // token row 0..31
    const int c0 = (t & 7) * 4;      // col quad within tile

    const float* p0 = wsp + (size_t)(2 * b) * 1024;
    const float* p1 = p0 + 1024;
    float4 a = *reinterpret_cast<const float4*>(p0 + m * 32 + c0);
    float4 c = *reinterpret_cast<const float4*>(p1 + m * 32 + c0);
    float4 s = *reinterpret_cast<const float4*>(scale + b * 32 + c0);
    float4 rv;
    rv.x = (a.x + c.x) * s.x;
    rv.y = (a.y + c.y) * s.y;
    rv.z = (a.z + c.z) * s.z;
    rv.w = (a.w + c.w) * s.w;
    *reinterpret_cast<float4*>(out + (size_t)m * OUT_F + b * 32 + c0) = rv;
}

extern "C" void kernel_launch(void* const* d_in, const int* in_sizes, int n_in,
                              void* d_out, int out_size, void* d_ws, size_t ws_size,
                              hipStream_t stream) {
    const float* x  = (const float*)d_in[0];
    const int*   wq = (const int*)d_in[1];   // int8-valued weights stored as int32
    const float* sc = (const float*)d_in[2];
    float* out = (float*)d_out;
    float* wsp = (float*)d_ws;               // 512 x 1024 f32 = 2 MB partials

    qlin_part<<<OUT_F / BN * KSPLIT, 256, 0, stream>>>(x, wq, wsp);
    qred<<<OUT_F / BN, 256, 0, stream>>>(wsp, sc, out);
}